// Round 13
// baseline (52.265 us; speedup 1.0000x reference)
//
#include <hip/hip_runtime.h>

#define TT 32768   // B*S tokens
#define S_LEN 1024
#define KC 8       // attention k-split chunks (128 rows each)

// intermediates; fully overwritten each call -> deterministic.
__device__ __align__(16) float g_Q[TT * 8];   // holds Q * 0.5 * log2(e)
__device__ __align__(16) float g_K[TT * 8];
__device__ __align__(16) float g_V[TT * 8];
__device__ __align__(16) float4 gp_acc[KC * 64 * 1024];
__device__ float gp_den[KC * 64 * 1024];
__device__ float g_coef[4][8][128];   // per-circuit uniform term coefficients

// ---------------------------------------------------------------------------
// Compile-time Pauli-backpropagation term tables (validated on HW in r11).
// ---------------------------------------------------------------------------
struct PTerm { unsigned ymask, zonly, tmask; float sgn; };
struct OTab { PTerm t[128]; int n; unsigned amask; };

constexpr unsigned conjZring(unsigned a) {
    for (int q = 7; q >= 0; --q) {
        const int c = q, tt = (q + 1) & 7;
        if ((a >> tt) & 1u) a ^= (1u << c);
    }
    return a;
}
constexpr unsigned conjXring(unsigned b) {
    for (int q = 7; q >= 0; --q) {
        const int c = q, tt = (q + 1) & 7;
        if ((b >> c) & 1u) b ^= (1u << tt);
    }
    return b;
}
constexpr int popc8(unsigned v) { int n = 0; for (int i = 0; i < 8; ++i) n += (v >> i) & 1; return n; }

constexpr OTab build_tab(int i) {
    OTab o{};
    o.n = 0;
    const unsigned a1 = conjZring(1u << i);
    o.amask = a1;
    const unsigned a3 = conjZring(a1);
    unsigned T = a1;
    while (true) {
        const unsigned b3 = conjXring(T);
        if (!(b3 & ~a3)) {
            const int k = popc8(T) + popc8(b3);
            const int idx = (k & 1) ? 100000 : o.n;   // odd phase => compile error
            o.t[idx].ymask = b3;
            o.t[idx].zonly = a3 & ~b3;
            o.t[idx].tmask = T;
            o.t[idx].sgn = ((k >> 1) & 1) ? -1.f : 1.f;
            o.n++;
        }
        if (T == 0) break;
        T = (T - 1) & a1;
    }
    return o;
}

constexpr OTab g_tab[8] = {build_tab(0), build_tab(1), build_tab(2), build_tab(3),
                           build_tab(4), build_tab(5), build_tab(6), build_tab(7)};
static_assert(g_tab[0].n >= 1 && g_tab[0].n <= 128, "term count");
static_assert(g_tab[7].n >= 1 && g_tab[7].n <= 128, "term count");

template <int I>
__device__ __forceinline__ void coef_one(const float s1[8], const float c1[8], float* dst)
{
    constexpr OTab tb = g_tab[I];
#pragma unroll
    for (int k = 0; k < tb.n; ++k) {
        float c = tb.t[k].sgn;
#pragma unroll
        for (int q = 0; q < 8; ++q) {
            if ((tb.t[k].tmask >> q) & 1) c *= s1[q];
            else if ((tb.amask >> q) & 1) c *= c1[q];
        }
        dst[k] = c;
    }
}

__global__ __launch_bounds__(64) void precoef(
    const float* __restrict__ wq, const float* __restrict__ wk,
    const float* __restrict__ wv, const float* __restrict__ wc)
{
    int tid = threadIdx.x;
    if (tid >= 32) return;
    int set = tid >> 3, i = tid & 7;
    const float* w = (set == 0) ? wq : (set == 1) ? wk : (set == 2) ? wv : wc;
    float s1[8], c1[8];
#pragma unroll
    for (int q = 0; q < 8; ++q) __sincosf(w[8 + q], &s1[q], &c1[q]);
    float* dst = &g_coef[set][i][0];
    switch (i) {
        case 0: coef_one<0>(s1, c1, dst); break;
        case 1: coef_one<1>(s1, c1, dst); break;
        case 2: coef_one<2>(s1, c1, dst); break;
        case 3: coef_one<3>(s1, c1, dst); break;
        case 4: coef_one<4>(s1, c1, dst); break;
        case 5: coef_one<5>(s1, c1, dst); break;
        case 6: coef_one<6>(s1, c1, dst); break;
        case 7: coef_one<7>(s1, c1, dst); break;
    }
}

template <int I>
__device__ __forceinline__ float eval_out(const float cs[8], const float sn[8],
                                          const float* __restrict__ coefI)
{
    constexpr OTab tb = g_tab[I];
    float acc = 0.f;
#pragma unroll
    for (int k = 0; k < tb.n; ++k) {
        float p = coefI[k];
#pragma unroll
        for (int q = 0; q < 8; ++q) {
            if ((tb.t[k].ymask >> q) & 1) p *= sn[q];
            else if ((tb.t[k].zonly >> q) & 1) p *= cs[q];
        }
        acc += p;
    }
    return acc;
}

__device__ __forceinline__ void eval_all(const float th[8],
                                         const float (*__restrict__ coef)[128],
                                         float ev[8])
{
    float cs[8], sn[8];
#pragma unroll
    for (int q = 0; q < 8; ++q) __sincosf(th[q], &sn[q], &cs[q]);
    ev[0] = eval_out<0>(cs, sn, coef[0]);
    ev[1] = eval_out<1>(cs, sn, coef[1]);
    ev[2] = eval_out<2>(cs, sn, coef[2]);
    ev[3] = eval_out<3>(cs, sn, coef[3]);
    ev[4] = eval_out<4>(cs, sn, coef[4]);
    ev[5] = eval_out<5>(cs, sn, coef[5]);
    ev[6] = eval_out<6>(cs, sn, coef[6]);
    ev[7] = eval_out<7>(cs, sn, coef[7]);
}

// Q is pre-scaled by 0.5*log2(e) so attention uses exp2 with a bare dot.
#define QSCALE 0.72134752044448170368f

__global__ __launch_bounds__(256) void qkv_pauli(
    const float* __restrict__ x, const float* __restrict__ wq,
    const float* __restrict__ wk, const float* __restrict__ wv)
{
    int t = blockIdx.x * 256 + threadIdx.x;
    int set = blockIdx.y;
    const float* w = (set == 0) ? wq : (set == 1) ? wk : wv;
    float* out = (set == 0) ? g_Q : (set == 1) ? g_K : g_V;
    float4 xa = ((const float4*)x)[t * 2];
    float4 xb = ((const float4*)x)[t * 2 + 1];
    float th[8] = {xa.x + w[0], xa.y + w[1], xa.z + w[2], xa.w + w[3],
                   xb.x + w[4], xb.y + w[5], xb.z + w[6], xb.w + w[7]};
    float ev[8];
    eval_all(th, g_coef[set], ev);
    float sc = (set == 0) ? QSCALE : 1.f;
#pragma unroll
    for (int i = 0; i < 8; ++i) ev[i] *= sc;
    ((float4*)out)[t * 2]     = make_float4(ev[0], ev[1], ev[2], ev[3]);
    ((float4*)out)[t * 2 + 1] = make_float4(ev[4], ev[5], ev[6], ev[7]);
}

// ---------------------------------------------------------------------------
// attention, k-split x KC. 4 q-rows per thread: each Ks/Vs broadcast read is
// reused 4x, cutting DS-pipe issue (the measured bottleneck) 4x.
// Block = 256 threads covers all 1024 q of one (b,h); kc chunk = 128 k-rows.
// ---------------------------------------------------------------------------
__global__ __launch_bounds__(256) void attn_part()
{
    __shared__ float4 Ks[128];
    __shared__ float4 Vs[128];
    int bh = blockIdx.x, kc = blockIdx.y;
    int b = bh >> 1, h = bh & 1;
    int tid = threadIdx.x;

    const float* Qb = g_Q + (size_t)b * S_LEN * 8 + h * 4;
    float4 qv0 = *(const float4*)(Qb + (size_t)(tid        ) * 8);
    float4 qv1 = *(const float4*)(Qb + (size_t)(tid + 256  ) * 8);
    float4 qv2 = *(const float4*)(Qb + (size_t)(tid + 512  ) * 8);
    float4 qv3 = *(const float4*)(Qb + (size_t)(tid + 768  ) * 8);

    if (tid < 128) {
        size_t row = (size_t)b * S_LEN + kc * 128 + tid;
        Ks[tid] = *(const float4*)(g_K + row * 8 + h * 4);
        Vs[tid] = *(const float4*)(g_V + row * 8 + h * 4);
    }
    __syncthreads();

    float den0 = 0.f, den1 = 0.f, den2 = 0.f, den3 = 0.f;
    float4 ac0 = make_float4(0.f, 0.f, 0.f, 0.f);
    float4 ac1 = make_float4(0.f, 0.f, 0.f, 0.f);
    float4 ac2 = make_float4(0.f, 0.f, 0.f, 0.f);
    float4 ac3 = make_float4(0.f, 0.f, 0.f, 0.f);
#pragma unroll 4
    for (int k = 0; k < 128; ++k) {
        float4 kk = Ks[k];
        float4 vv = Vs[k];
        float s0 = qv0.x * kk.x + qv0.y * kk.y + qv0.z * kk.z + qv0.w * kk.w;
        float s1 = qv1.x * kk.x + qv1.y * kk.y + qv1.z * kk.z + qv1.w * kk.w;
        float s2 = qv2.x * kk.x + qv2.y * kk.y + qv2.z * kk.z + qv2.w * kk.w;
        float s3 = qv3.x * kk.x + qv3.y * kk.y + qv3.z * kk.z + qv3.w * kk.w;
        float e0 = exp2f(s0), e1 = exp2f(s1), e2 = exp2f(s2), e3 = exp2f(s3);
        den0 += e0; den1 += e1; den2 += e2; den3 += e3;
        ac0.x += e0 * vv.x; ac0.y += e0 * vv.y; ac0.z += e0 * vv.z; ac0.w += e0 * vv.w;
        ac1.x += e1 * vv.x; ac1.y += e1 * vv.y; ac1.z += e1 * vv.z; ac1.w += e1 * vv.w;
        ac2.x += e2 * vv.x; ac2.y += e2 * vv.y; ac2.z += e2 * vv.z; ac2.w += e2 * vv.w;
        ac3.x += e3 * vv.x; ac3.y += e3 * vv.y; ac3.z += e3 * vv.z; ac3.w += e3 * vv.w;
    }
    int base = kc * 65536 + bh * 1024 + tid;
    gp_acc[base]       = ac0;  gp_den[base]       = den0;
    gp_acc[base + 256] = ac1;  gp_den[base + 256] = den1;
    gp_acc[base + 512] = ac2;  gp_den[base + 512] = den2;
    gp_acc[base + 768] = ac3;  gp_den[base + 768] = den3;
}

// ---- output circuit with fused k-split merge ----
__global__ __launch_bounds__(256) void outc_pauli(
    const float* __restrict__ wc, float* __restrict__ out)
{
    int t = blockIdx.x * 256 + threadIdx.x;
    int b = t >> 10, s = t & 1023;
    float th[8];
#pragma unroll
    for (int h = 0; h < 2; ++h) {
        float4 A = make_float4(0.f, 0.f, 0.f, 0.f);
        float D = 0.f;
#pragma unroll
        for (int kc = 0; kc < KC; ++kc) {
            int idx = kc * 65536 + (b * 2 + h) * 1024 + s;
            float4 a = gp_acc[idx];
            A.x += a.x; A.y += a.y; A.z += a.z; A.w += a.w;
            D += gp_den[idx];
        }
        float inv = 1.f / D;
        th[h * 4 + 0] = A.x * inv + wc[h * 4 + 0];
        th[h * 4 + 1] = A.y * inv + wc[h * 4 + 1];
        th[h * 4 + 2] = A.z * inv + wc[h * 4 + 2];
        th[h * 4 + 3] = A.w * inv + wc[h * 4 + 3];
    }
    float ev[8];
    eval_all(th, g_coef[3], ev);
    ((float4*)out)[t * 2]     = make_float4(ev[0], ev[1], ev[2], ev[3]);
    ((float4*)out)[t * 2 + 1] = make_float4(ev[4], ev[5], ev[6], ev[7]);
}

extern "C" void kernel_launch(void* const* d_in, const int* in_sizes, int n_in,
                              void* d_out, int out_size, void* d_ws, size_t ws_size,
                              hipStream_t stream)
{
    const float* x  = (const float*)d_in[0];
    const float* wq = (const float*)d_in[1];
    const float* wk = (const float*)d_in[2];
    const float* wv = (const float*)d_in[3];
    const float* wc = (const float*)d_in[4];

    precoef<<<1, 64, 0, stream>>>(wq, wk, wv, wc);
    qkv_pauli<<<dim3(TT / 256, 3), 256, 0, stream>>>(x, wq, wk, wv);
    attn_part<<<dim3(64, KC), 256, 0, stream>>>();
    outc_pauli<<<TT / 256, 256, 0, stream>>>(wc, (float*)d_out);
}

// Round 14
// 45.519 us; speedup vs baseline: 1.1482x; 1.1482x over previous
//
#include <hip/hip_runtime.h>

#define TT 32768   // B*S tokens
#define S_LEN 1024
#define KC 8       // attention k-split chunks (128 rows each)

// intermediates; fully overwritten each call -> deterministic.
__device__ __align__(16) float g_Q[TT * 8];   // holds Q * 0.5 * log2(e)
__device__ __align__(16) float g_K[TT * 8];
__device__ __align__(16) float g_V[TT * 8];
__device__ __align__(16) float4 gp_acc[KC * 64 * 1024];
__device__ float gp_den[KC * 64 * 1024];
__device__ float g_coef[4][8][128];   // per-circuit uniform term coefficients

// ---------------------------------------------------------------------------
// Compile-time Pauli-backpropagation term tables (validated on HW in r11).
// ---------------------------------------------------------------------------
struct PTerm { unsigned ymask, zonly, tmask; float sgn; };
struct OTab { PTerm t[128]; int n; unsigned amask; };

constexpr unsigned conjZring(unsigned a) {
    for (int q = 7; q >= 0; --q) {
        const int c = q, tt = (q + 1) & 7;
        if ((a >> tt) & 1u) a ^= (1u << c);
    }
    return a;
}
constexpr unsigned conjXring(unsigned b) {
    for (int q = 7; q >= 0; --q) {
        const int c = q, tt = (q + 1) & 7;
        if ((b >> c) & 1u) b ^= (1u << tt);
    }
    return b;
}
constexpr int popc8(unsigned v) { int n = 0; for (int i = 0; i < 8; ++i) n += (v >> i) & 1; return n; }

constexpr OTab build_tab(int i) {
    OTab o{};
    o.n = 0;
    const unsigned a1 = conjZring(1u << i);
    o.amask = a1;
    const unsigned a3 = conjZring(a1);
    unsigned T = a1;
    while (true) {
        const unsigned b3 = conjXring(T);
        if (!(b3 & ~a3)) {
            const int k = popc8(T) + popc8(b3);
            const int idx = (k & 1) ? 100000 : o.n;   // odd phase => compile error
            o.t[idx].ymask = b3;
            o.t[idx].zonly = a3 & ~b3;
            o.t[idx].tmask = T;
            o.t[idx].sgn = ((k >> 1) & 1) ? -1.f : 1.f;
            o.n++;
        }
        if (T == 0) break;
        T = (T - 1) & a1;
    }
    return o;
}

constexpr OTab g_tab[8] = {build_tab(0), build_tab(1), build_tab(2), build_tab(3),
                           build_tab(4), build_tab(5), build_tab(6), build_tab(7)};
static_assert(g_tab[0].n >= 1 && g_tab[0].n <= 128, "term count");
static_assert(g_tab[7].n >= 1 && g_tab[7].n <= 128, "term count");

template <int I>
__device__ __forceinline__ void coef_one(const float s1[8], const float c1[8], float* dst)
{
    constexpr OTab tb = g_tab[I];
#pragma unroll
    for (int k = 0; k < tb.n; ++k) {
        float c = tb.t[k].sgn;
#pragma unroll
        for (int q = 0; q < 8; ++q) {
            if ((tb.t[k].tmask >> q) & 1) c *= s1[q];
            else if ((tb.amask >> q) & 1) c *= c1[q];
        }
        dst[k] = c;
    }
}

__global__ __launch_bounds__(64) void precoef(
    const float* __restrict__ wq, const float* __restrict__ wk,
    const float* __restrict__ wv, const float* __restrict__ wc)
{
    int tid = threadIdx.x;
    if (tid >= 32) return;
    int set = tid >> 3, i = tid & 7;
    const float* w = (set == 0) ? wq : (set == 1) ? wk : (set == 2) ? wv : wc;
    float s1[8], c1[8];
#pragma unroll
    for (int q = 0; q < 8; ++q) __sincosf(w[8 + q], &s1[q], &c1[q]);
    float* dst = &g_coef[set][i][0];
    switch (i) {
        case 0: coef_one<0>(s1, c1, dst); break;
        case 1: coef_one<1>(s1, c1, dst); break;
        case 2: coef_one<2>(s1, c1, dst); break;
        case 3: coef_one<3>(s1, c1, dst); break;
        case 4: coef_one<4>(s1, c1, dst); break;
        case 5: coef_one<5>(s1, c1, dst); break;
        case 6: coef_one<6>(s1, c1, dst); break;
        case 7: coef_one<7>(s1, c1, dst); break;
    }
}

template <int I>
__device__ __forceinline__ float eval_out(const float cs[8], const float sn[8],
                                          const float* __restrict__ coefI)
{
    constexpr OTab tb = g_tab[I];
    float acc = 0.f;
#pragma unroll
    for (int k = 0; k < tb.n; ++k) {
        float p = coefI[k];
#pragma unroll
        for (int q = 0; q < 8; ++q) {
            if ((tb.t[k].ymask >> q) & 1) p *= sn[q];
            else if ((tb.t[k].zonly >> q) & 1) p *= cs[q];
        }
        acc += p;
    }
    return acc;
}

__device__ __forceinline__ void eval_all(const float th[8],
                                         const float (*__restrict__ coef)[128],
                                         float ev[8])
{
    float cs[8], sn[8];
#pragma unroll
    for (int q = 0; q < 8; ++q) __sincosf(th[q], &sn[q], &cs[q]);
    ev[0] = eval_out<0>(cs, sn, coef[0]);
    ev[1] = eval_out<1>(cs, sn, coef[1]);
    ev[2] = eval_out<2>(cs, sn, coef[2]);
    ev[3] = eval_out<3>(cs, sn, coef[3]);
    ev[4] = eval_out<4>(cs, sn, coef[4]);
    ev[5] = eval_out<5>(cs, sn, coef[5]);
    ev[6] = eval_out<6>(cs, sn, coef[6]);
    ev[7] = eval_out<7>(cs, sn, coef[7]);
}

// Q is pre-scaled by 0.5*log2(e) so attention uses native v_exp_f32 (= exp2).
#define QSCALE 0.72134752044448170368f

// single-instruction exp2 on the trans pipe; non-volatile so it schedules.
__device__ __forceinline__ float fexp2(float s)
{
    float r;
    asm("v_exp_f32 %0, %1" : "=v"(r) : "v"(s));
    return r;
}

__global__ __launch_bounds__(256) void qkv_pauli(
    const float* __restrict__ x, const float* __restrict__ wq,
    const float* __restrict__ wk, const float* __restrict__ wv)
{
    int t = blockIdx.x * 256 + threadIdx.x;
    int set = blockIdx.y;
    const float* w = (set == 0) ? wq : (set == 1) ? wk : wv;
    float* out = (set == 0) ? g_Q : (set == 1) ? g_K : g_V;
    float4 xa = ((const float4*)x)[t * 2];
    float4 xb = ((const float4*)x)[t * 2 + 1];
    float th[8] = {xa.x + w[0], xa.y + w[1], xa.z + w[2], xa.w + w[3],
                   xb.x + w[4], xb.y + w[5], xb.z + w[6], xb.w + w[7]};
    float ev[8];
    eval_all(th, g_coef[set], ev);
    float sc = (set == 0) ? QSCALE : 1.f;
#pragma unroll
    for (int i = 0; i < 8; ++i) ev[i] *= sc;
    ((float4*)out)[t * 2]     = make_float4(ev[0], ev[1], ev[2], ev[3]);
    ((float4*)out)[t * 2 + 1] = make_float4(ev[4], ev[5], ev[6], ev[7]);
}

// ---------------------------------------------------------------------------
// attention: grid (64 bh, 2 qc, 8 kc) = 1024 blocks (4 blocks/CU, 4 w/SIMD).
// 2 q-rows per thread (independent chains), unroll 8, native exp.
// ---------------------------------------------------------------------------
__global__ __launch_bounds__(256) void attn_part()
{
    __shared__ float4 Ks[128];
    __shared__ float4 Vs[128];
    int bh = blockIdx.x, qc = blockIdx.y, kc = blockIdx.z;
    int b = bh >> 1, h = bh & 1;
    int tid = threadIdx.x;

    const float* Qb = g_Q + (size_t)b * S_LEN * 8 + h * 4;
    int q0 = qc * 512 + tid;
    float4 qv0 = *(const float4*)(Qb + (size_t)q0 * 8);
    float4 qv1 = *(const float4*)(Qb + (size_t)(q0 + 256) * 8);

    size_t rowbase = (size_t)b * S_LEN + kc * 128;
    if (tid < 128) {
        Ks[tid] = *(const float4*)(g_K + (rowbase + tid) * 8 + h * 4);
    } else {
        int r = tid - 128;
        Vs[r] = *(const float4*)(g_V + (rowbase + r) * 8 + h * 4);
    }
    __syncthreads();

    float den0 = 0.f, den1 = 0.f;
    float4 ac0 = make_float4(0.f, 0.f, 0.f, 0.f);
    float4 ac1 = make_float4(0.f, 0.f, 0.f, 0.f);
#pragma unroll 8
    for (int k = 0; k < 128; ++k) {
        float4 kk = Ks[k];
        float4 vv = Vs[k];
        float s0 = qv0.x * kk.x + qv0.y * kk.y + qv0.z * kk.z + qv0.w * kk.w;
        float s1 = qv1.x * kk.x + qv1.y * kk.y + qv1.z * kk.z + qv1.w * kk.w;
        float e0 = fexp2(s0);
        float e1 = fexp2(s1);
        den0 += e0; den1 += e1;
        ac0.x += e0 * vv.x; ac0.y += e0 * vv.y; ac0.z += e0 * vv.z; ac0.w += e0 * vv.w;
        ac1.x += e1 * vv.x; ac1.y += e1 * vv.y; ac1.z += e1 * vv.z; ac1.w += e1 * vv.w;
    }
    int base = kc * 65536 + bh * 1024 + q0;
    gp_acc[base]       = ac0;  gp_den[base]       = den0;
    gp_acc[base + 256] = ac1;  gp_den[base + 256] = den1;
}

// ---- output circuit with fused k-split merge ----
__global__ __launch_bounds__(256) void outc_pauli(
    const float* __restrict__ wc, float* __restrict__ out)
{
    int t = blockIdx.x * 256 + threadIdx.x;
    int b = t >> 10, s = t & 1023;
    float th[8];
#pragma unroll
    for (int h = 0; h < 2; ++h) {
        float4 A = make_float4(0.f, 0.f, 0.f, 0.f);
        float D = 0.f;
#pragma unroll
        for (int kc = 0; kc < KC; ++kc) {
            int idx = kc * 65536 + (b * 2 + h) * 1024 + s;
            float4 a = gp_acc[idx];
            A.x += a.x; A.y += a.y; A.z += a.z; A.w += a.w;
            D += gp_den[idx];
        }
        float inv = 1.f / D;
        th[h * 4 + 0] = A.x * inv + wc[h * 4 + 0];
        th[h * 4 + 1] = A.y * inv + wc[h * 4 + 1];
        th[h * 4 + 2] = A.z * inv + wc[h * 4 + 2];
        th[h * 4 + 3] = A.w * inv + wc[h * 4 + 3];
    }
    float ev[8];
    eval_all(th, g_coef[3], ev);
    ((float4*)out)[t * 2]     = make_float4(ev[0], ev[1], ev[2], ev[3]);
    ((float4*)out)[t * 2 + 1] = make_float4(ev[4], ev[5], ev[6], ev[7]);
}

extern "C" void kernel_launch(void* const* d_in, const int* in_sizes, int n_in,
                              void* d_out, int out_size, void* d_ws, size_t ws_size,
                              hipStream_t stream)
{
    const float* x  = (const float*)d_in[0];
    const float* wq = (const float*)d_in[1];
    const float* wk = (const float*)d_in[2];
    const float* wv = (const float*)d_in[3];
    const float* wc = (const float*)d_in[4];

    precoef<<<1, 64, 0, stream>>>(wq, wk, wv, wc);
    qkv_pauli<<<dim3(TT / 256, 3), 256, 0, stream>>>(x, wq, wk, wv);
    attn_part<<<dim3(64, 2, KC), 256, 0, stream>>>();
    outc_pauli<<<TT / 256, 256, 0, stream>>>(wc, (float*)d_out);
}